// Round 1
// baseline (17166.692 us; speedup 1.0000x reference)
//
#include <hip/hip_runtime.h>
#include <math.h>

#define NH 8
#define DKH 256
#define SEQ 1024
#define BSZ 8
#define DMODEL 2048
#define DINNER 4096
#define DSTATE 16
#define DTRANK 128

// workspace offsets (floats)
#define OFF_XZ   0ULL           // 8192 x 8192  (x cols 0..4095, z cols 4096..8191)
#define OFF_Q    0ULL           // 8192 x 2048  (aliases xz; also att output)
#define OFF_K    16777216ULL    // kT: (8*8*256) x 1024
#define OFF_V    33554432ULL    // 8192 x 2048
#define OFF_DT   67108864ULL    // 8192 x 4096
#define OFF_DBC  100663296ULL   // 8192 x 160
#define OFF_WC   101974016ULL   // 2048 x 160

#define FLAG_BIAS 1
#define FLAG_SOFTPLUS 2
#define FLAG_KT 4

#define BM 64
#define BN 64
#define BK 16

__global__ __launch_bounds__(256) void gemm_f32(
    const float* __restrict__ A, const float* __restrict__ B,
    const float* __restrict__ bias, float* __restrict__ C,
    int M, int N, int K, int lda, int ldb, int ldc, int flags)
{
    __shared__ float As[BK][BM + 4];   // row stride 68 floats (16B aligned)
    __shared__ float Bs[BK][BN + 4];
    int tid = threadIdx.x;
    int tm = tid >> 4, tn = tid & 15;
    int bm = blockIdx.y * BM, bn = blockIdx.x * BN;
    float acc[4][4] = {};

    for (int k0 = 0; k0 < K; k0 += BK) {
        // A tile: 64 rows x 16 cols, idx = r*16 + c
        #pragma unroll
        for (int i = 0; i < 4; i++) {
            int idx = tid + i * 256;
            int r = idx >> 4, c = idx & 15;
            int gr = bm + r, gc = k0 + c;
            float v = 0.f;
            if (gr < M && gc < K) v = A[(size_t)gr * lda + gc];
            As[c][r] = v;
        }
        // B tile: 16 rows x 64 cols, idx = r*64 + c
        #pragma unroll
        for (int i = 0; i < 4; i++) {
            int idx = tid + i * 256;
            int r = idx >> 6, c = idx & 63;
            int gr = k0 + r, gc = bn + c;
            float v = 0.f;
            if (gr < K && gc < N) v = B[(size_t)gr * ldb + gc];
            Bs[r][c] = v;
        }
        __syncthreads();
        #pragma unroll
        for (int kk = 0; kk < BK; kk++) {
            float4 a4 = *(const float4*)&As[kk][tm * 4];
            float4 b4 = *(const float4*)&Bs[kk][tn * 4];
            float av[4] = {a4.x, a4.y, a4.z, a4.w};
            float bv[4] = {b4.x, b4.y, b4.z, b4.w};
            #pragma unroll
            for (int i = 0; i < 4; i++)
                #pragma unroll
                for (int j = 0; j < 4; j++)
                    acc[i][j] += av[i] * bv[j];
        }
        __syncthreads();
    }

    #pragma unroll
    for (int i = 0; i < 4; i++) {
        int row = bm + tm * 4 + i;
        if (row >= M) continue;
        #pragma unroll
        for (int j = 0; j < 4; j++) {
            int col = bn + tn * 4 + j;
            if (col >= N) continue;
            float val = acc[i][j];
            if (flags & FLAG_BIAS) val += bias[col];
            if (flags & FLAG_SOFTPLUS) val = (val > 20.f) ? val : log1pf(__expf(val));
            if (flags & FLAG_KT) {
                int bi = row >> 10, jj = row & 1023;
                int hh = col >> 8, dk2 = col & 255;
                C[((size_t)((bi * NH + hh) * DKH + dk2)) * SEQ + jj] = val;
            } else {
                C[(size_t)row * ldc + col] = val;
            }
        }
    }
}

#define TQ 8
__global__ __launch_bounds__(256) void attention(
    const float* __restrict__ q, const float* __restrict__ kt,
    const float* __restrict__ v, float* __restrict__ attout)
{
    __shared__ float qs[TQ][DKH];
    __shared__ float sc[TQ][SEQ];
    __shared__ float rowstat[TQ];
    __shared__ float red[8];

    int tid = threadIdx.x;
    int bidx = blockIdx.x;
    int qt = bidx & 127;
    int h = (bidx >> 7) & 7;
    int b = bidx >> 10;
    int q0 = qt * TQ;

    #pragma unroll
    for (int r = 0; r < TQ; r++)
        qs[r][tid] = q[((size_t)(b * SEQ + q0 + r)) * DMODEL + h * DKH + tid];
    __syncthreads();

    // scores: thread handles keys 4*tid..4*tid+3
    {
        float acc[TQ][4] = {};
        const float* kbase = kt + ((size_t)(b * NH + h)) * DKH * SEQ + 4 * tid;
        for (int d = 0; d < DKH; d++) {
            float4 kv = *(const float4*)(kbase + (size_t)d * SEQ);
            #pragma unroll
            for (int r = 0; r < TQ; r++) {
                float qv = qs[r][d];
                acc[r][0] += qv * kv.x; acc[r][1] += qv * kv.y;
                acc[r][2] += qv * kv.z; acc[r][3] += qv * kv.w;
            }
        }
        #pragma unroll
        for (int r = 0; r < TQ; r++) {
            sc[r][4 * tid + 0] = acc[r][0] * 0.0625f;
            sc[r][4 * tid + 1] = acc[r][1] * 0.0625f;
            sc[r][4 * tid + 2] = acc[r][2] * 0.0625f;
            sc[r][4 * tid + 3] = acc[r][3] * 0.0625f;
        }
    }
    __syncthreads();

    // softmax per row
    for (int r = 0; r < TQ; r++) {
        float m = -1e30f;
        for (int j = tid; j < SEQ; j += 256) m = fmaxf(m, sc[r][j]);
        #pragma unroll
        for (int off = 1; off < 64; off <<= 1) m = fmaxf(m, __shfl_xor(m, off));
        if ((tid & 63) == 0) red[tid >> 6] = m;
        __syncthreads();
        m = fmaxf(fmaxf(red[0], red[1]), fmaxf(red[2], red[3]));
        __syncthreads();
        float s = 0.f;
        for (int j = tid; j < SEQ; j += 256) {
            float e = __expf(sc[r][j] - m);
            sc[r][j] = e;
            s += e;
        }
        #pragma unroll
        for (int off = 1; off < 64; off <<= 1) s += __shfl_xor(s, off);
        if ((tid & 63) == 0) red[tid >> 6] = s;
        __syncthreads();
        if (tid == 0) rowstat[r] = 1.f / (red[0] + red[1] + red[2] + red[3]);
        __syncthreads();
    }

    // PV: thread = output dim d
    {
        float acc[TQ] = {};
        const float* vbase = v + (size_t)b * SEQ * DMODEL + h * DKH + tid;
        for (int j0 = 0; j0 < SEQ; j0 += 4) {
            float vv0 = vbase[(size_t)(j0 + 0) * DMODEL];
            float vv1 = vbase[(size_t)(j0 + 1) * DMODEL];
            float vv2 = vbase[(size_t)(j0 + 2) * DMODEL];
            float vv3 = vbase[(size_t)(j0 + 3) * DMODEL];
            #pragma unroll
            for (int r = 0; r < TQ; r++) {
                float4 p = *(const float4*)&sc[r][j0];
                acc[r] += p.x * vv0 + p.y * vv1 + p.z * vv2 + p.w * vv3;
            }
        }
        #pragma unroll
        for (int r = 0; r < TQ; r++)
            attout[((size_t)(b * SEQ + q0 + r)) * DMODEL + h * DKH + tid] = acc[r] * rowstat[r];
    }
}

// fused conv1d + silu + selective scan + D_skip + silu(z) gating; y written in place over x
__global__ __launch_bounds__(256) void mamba_scan(
    float* __restrict__ xz, const float* __restrict__ dt,
    const float* __restrict__ dbc, const float* __restrict__ A_log,
    const float* __restrict__ conv_w, const float* __restrict__ conv_b,
    const float* __restrict__ D_skip)
{
    int tid = threadIdx.x;
    int n = tid & 15;
    int dd = tid >> 4;                 // 0..15
    int gb = blockIdx.x;               // 0..2047
    int b = gb >> 8;
    int d = ((gb & 255) << 4) + dd;    // 0..4095

    float A_n = -__expf(A_log[d * DSTATE + n]);
    float cw0 = conv_w[d * 4 + 0], cw1 = conv_w[d * 4 + 1];
    float cw2 = conv_w[d * 4 + 2], cw3 = conv_w[d * 4 + 3];
    float cb = conv_b[d];
    float dsk = D_skip[d];

    float h = 0.f;
    float w0 = 0.f, w1 = 0.f, w2 = 0.f;
    size_t rowx = (size_t)b * SEQ * 8192 + d;
    size_t rowdt = (size_t)b * SEQ * DINNER + d;
    size_t rowbc = (size_t)b * SEQ * 160;

    for (int t = 0; t < SEQ; t++) {
        float xr = xz[rowx + (size_t)t * 8192];
        float dtv = dt[rowdt + (size_t)t * DINNER];
        float Bv = dbc[rowbc + t * 160 + DTRANK + n];
        float Cv = dbc[rowbc + t * 160 + DTRANK + DSTATE + n];

        float xc = cw0 * w0 + cw1 * w1 + cw2 * w2 + cw3 * xr + cb;
        w0 = w1; w1 = w2; w2 = xr;
        float xs = xc / (1.f + __expf(-xc));   // silu

        float dA = __expf(dtv * A_n);
        h = dA * h + dtv * Bv * xs;
        float p = h * Cv;
        p += __shfl_xor(p, 1, 16);
        p += __shfl_xor(p, 2, 16);
        p += __shfl_xor(p, 4, 16);
        p += __shfl_xor(p, 8, 16);

        float y = p + dsk * xs;
        float zv = xz[rowx + (size_t)t * 8192 + DINNER];
        y = y * (zv / (1.f + __expf(-zv)));
        if (n == 0) xz[rowx + (size_t)t * 8192] = y;
    }
}

extern "C" void kernel_launch(void* const* d_in, const int* in_sizes, int n_in,
                              void* d_out, int out_size, void* d_ws, size_t ws_size,
                              hipStream_t stream) {
    const float* imgF   = (const float*)d_in[0];
    const float* kf     = (const float*)d_in[1];
    const float* Wq     = (const float*)d_in[2];
    const float* bq     = (const float*)d_in[3];
    const float* Wk     = (const float*)d_in[4];
    const float* bk     = (const float*)d_in[5];
    const float* Wv     = (const float*)d_in[6];
    const float* bv     = (const float*)d_in[7];
    const float* Wo     = (const float*)d_in[8];
    const float* bo     = (const float*)d_in[9];
    const float* W_in   = (const float*)d_in[10];
    const float* conv_w = (const float*)d_in[11];
    const float* conv_b = (const float*)d_in[12];
    const float* W_extra= (const float*)d_in[13];
    const float* W_xproj= (const float*)d_in[14];
    const float* W_dt   = (const float*)d_in[15];
    const float* b_dt   = (const float*)d_in[16];
    const float* A_log  = (const float*)d_in[17];
    const float* D_skip = (const float*)d_in[18];
    const float* W_out  = (const float*)d_in[19];
    float* out = (float*)d_out;
    float* ws  = (float*)d_ws;

    dim3 blk(256);
    auto gg = [](int M, int N) { return dim3((N + BN - 1) / BN, (M + BM - 1) / BM); };

    // Wcomb = W_extra @ W_xproj   (2048 x 160)
    gemm_f32<<<gg(2048, 160), blk, 0, stream>>>(W_extra, W_xproj, nullptr, ws + OFF_WC,
        2048, 160, 4096, 4096, 160, 160, 0);
    // q = imgF @ Wq + bq
    gemm_f32<<<gg(8192, 2048), blk, 0, stream>>>(imgF, Wq, bq, ws + OFF_Q,
        8192, 2048, 2048, 2048, 2048, 2048, FLAG_BIAS);
    // kT (transposed per (b,h)) = imgF @ Wk + bk
    gemm_f32<<<gg(8192, 2048), blk, 0, stream>>>(imgF, Wk, bk, ws + OFF_K,
        8192, 2048, 2048, 2048, 2048, 0, FLAG_BIAS | FLAG_KT);
    // v = imgF @ Wv + bv
    gemm_f32<<<gg(8192, 2048), blk, 0, stream>>>(imgF, Wv, bv, ws + OFF_V,
        8192, 2048, 2048, 2048, 2048, 2048, FLAG_BIAS);
    // attention, in-place into q buffer
    attention<<<dim3(BSZ * NH * (SEQ / TQ)), blk, 0, stream>>>(
        ws + OFF_Q, ws + OFF_K, ws + OFF_V, ws + OFF_Q);
    // out0 = att @ Wo + bo
    gemm_f32<<<gg(8192, 2048), blk, 0, stream>>>(ws + OFF_Q, Wo, bo, out,
        8192, 2048, 2048, 2048, 2048, 2048, FLAG_BIAS);
    // xz = imgF @ W_in   (overwrites q/k/v region)
    gemm_f32<<<gg(8192, 8192), blk, 0, stream>>>(imgF, W_in, nullptr, ws + OFF_XZ,
        8192, 8192, 2048, 2048, 8192, 8192, 0);
    // dbc = kf @ Wcomb
    gemm_f32<<<gg(8192, 160), blk, 0, stream>>>(kf, ws + OFF_WC, nullptr, ws + OFF_DBC,
        8192, 160, 2048, 2048, 160, 160, 0);
    // dt = softplus(dbc[:, :128] @ W_dt + b_dt)
    gemm_f32<<<gg(8192, 4096), blk, 0, stream>>>(ws + OFF_DBC, W_dt, b_dt, ws + OFF_DT,
        8192, 4096, 128, 160, 4096, 4096, FLAG_BIAS | FLAG_SOFTPLUS);
    // fused conv + scan + gating, y in place over x
    mamba_scan<<<dim3(2048), blk, 0, stream>>>(ws + OFF_XZ, ws + OFF_DT, ws + OFF_DBC,
        A_log, conv_w, conv_b, D_skip);
    // out1 = y @ W_out
    gemm_f32<<<gg(8192, 2048), blk, 0, stream>>>(ws + OFF_XZ, W_out, nullptr, out + 16777216,
        8192, 2048, 4096, 8192, 2048, 2048, 0);
}

// Round 2
// 6697.394 us; speedup vs baseline: 2.5632x; 2.5632x over previous
//
#include <hip/hip_runtime.h>
#include <math.h>

#define NH 8
#define DKH 256
#define SEQ 1024
#define BSZ 8
#define DMODEL 2048
#define DINNER 4096
#define DSTATE 16
#define DTRANK 128

#define MiB 1048576ULL

// ---------------- workspace byte offsets ----------------
// mamba phase
#define O_XZ    (0*MiB)                  // f32 8192x8192 (x cols 0..4095, z 4096..8191)
#define O_IMGH  (256*MiB)                // bf16 8192x2048 imgF hi
#define O_IMGL  (288*MiB)
#define O_WINTH (320*MiB)                // bf16 8192x2048  W_in^T hi
#define O_WINTL (352*MiB)
#define O_WCOMB (384*MiB)                // f32 2048x160
#define O_DBC   (384*MiB + 1310720ULL)   // f32 8192x160   (ends exactly at 409206784)
#define O_DT    (256*MiB)                // f32 8192x4096 (after xz GEMM)
#define O_YH    (256*MiB)                // bf16 8192x4096 (after scan)
#define O_YL    (320*MiB)
#define O_WOUTH (0*MiB)                  // bf16 2048x4096 (after y convert)
#define O_WOUTL (16*MiB)
// attention phase (after out1)
#define O_IMGH2 (0*MiB)
#define O_IMGL2 (32*MiB)
#define O_WQH   (64*MiB)
#define O_WQL   (72*MiB)
#define O_WKH   (80*MiB)
#define O_WKL   (88*MiB)
#define O_WVH   (96*MiB)
#define O_WVL   (104*MiB)
#define O_WOH   (112*MiB)
#define O_WOL   (120*MiB)
#define O_QF    (128*MiB)                // f32 8192x2048
#define O_KTF   (192*MiB)                // f32 kT (8*8*256) x 1024
#define O_VF    (256*MiB)
#define O_ATTH  (320*MiB)                // bf16 8192x2048
#define O_ATTL  (352*MiB)

#define FLAG_BIAS 1
#define FLAG_SOFTPLUS 2
#define FLAG_KT 4

typedef __attribute__((ext_vector_type(8))) short bf16x8;
typedef __attribute__((ext_vector_type(4))) float f32x4;
typedef const void __attribute__((address_space(1))) gv_t;
typedef void __attribute__((address_space(3))) lv_t;

__device__ __forceinline__ unsigned short f2bf(float x) {
    unsigned u = __float_as_uint(x);
    unsigned r = u + 0x7FFFu + ((u >> 16) & 1u);
    return (unsigned short)(r >> 16);
}
__device__ __forceinline__ float bf2f(unsigned short h) {
    return __uint_as_float((unsigned)h << 16);
}

// ---------------- conversion kernels ----------------
__global__ __launch_bounds__(256) void cvt_hilo(
    const float* __restrict__ in, unsigned short* __restrict__ hi,
    unsigned short* __restrict__ lo, int n4)
{
    int i = blockIdx.x * 256 + threadIdx.x;
    if (i >= n4) return;
    float4 x = ((const float4*)in)[i];
    ushort4 h, l;
    h.x = f2bf(x.x); l.x = f2bf(x.x - bf2f(h.x));
    h.y = f2bf(x.y); l.y = f2bf(x.y - bf2f(h.y));
    h.z = f2bf(x.z); l.z = f2bf(x.z - bf2f(h.z));
    h.w = f2bf(x.w); l.w = f2bf(x.w - bf2f(h.w));
    ((ushort4*)hi)[i] = h;
    ((ushort4*)lo)[i] = l;
}

// W: K x N row-major f32  ->  T: N x K row-major bf16 hi/lo
__global__ __launch_bounds__(256) void tcvt(
    const float* __restrict__ W, unsigned short* __restrict__ Thi,
    unsigned short* __restrict__ Tlo, int K, int N)
{
    __shared__ float t[32][33];
    int tx = threadIdx.x & 31, ty = threadIdx.x >> 5;
    int k0 = blockIdx.y * 32, n0 = blockIdx.x * 32;
    #pragma unroll
    for (int i = 0; i < 32; i += 8)
        t[ty + i][tx] = W[(size_t)(k0 + ty + i) * N + n0 + tx];
    __syncthreads();
    #pragma unroll
    for (int i = 0; i < 32; i += 8) {
        float v = t[tx][ty + i];
        size_t o = (size_t)(n0 + ty + i) * K + k0 + tx;
        unsigned short h = f2bf(v);
        Thi[o] = h;
        Tlo[o] = f2bf(v - bf2f(h));
    }
}

// y lives in xz cols 0..4095 (row stride 8192); pack to bf16 hi/lo 8192x4096
__global__ __launch_bounds__(256) void ycvt(
    const float* __restrict__ xz, unsigned short* __restrict__ hi,
    unsigned short* __restrict__ lo)
{
    int i = blockIdx.x * 256 + threadIdx.x;   // 0 .. 8192*1024-1
    int r = i >> 10, c4 = (i & 1023) << 2;
    float4 x = *(const float4*)&xz[(size_t)r * 8192 + c4];
    ushort4 h, l;
    h.x = f2bf(x.x); l.x = f2bf(x.x - bf2f(h.x));
    h.y = f2bf(x.y); l.y = f2bf(x.y - bf2f(h.y));
    h.z = f2bf(x.z); l.z = f2bf(x.z - bf2f(h.z));
    h.w = f2bf(x.w); l.w = f2bf(x.w - bf2f(h.w));
    size_t o = ((size_t)r * 4096 + c4) >> 2;
    ((ushort4*)hi)[o] = h;
    ((ushort4*)lo)[o] = l;
}

// ---------------- MFMA split GEMM ----------------
// C(MxN,f32) = (Ahi+Alo)(Bhi) + Ahi*Blo;  A: MxK row-major bf16, B given as B^T: NxK row-major bf16
__device__ __forceinline__ void gload16(const unsigned short* g, unsigned short* l) {
    __builtin_amdgcn_global_load_lds((gv_t*)g, (lv_t*)l, 16, 0, 0);
}

__global__ __launch_bounds__(256) void gemm_mfma3(
    const unsigned short* __restrict__ Ahi, const unsigned short* __restrict__ Alo,
    const unsigned short* __restrict__ Bhi, const unsigned short* __restrict__ Blo,
    const float* __restrict__ bias, float* __restrict__ C,
    int M, int N, int K, int flags)
{
    __shared__ unsigned short sAh[128*32], sAl[128*32], sBh[128*32], sBl[128*32];
    int tid = threadIdx.x;
    int lane = tid & 63, wv = tid >> 6;
    int wm = wv >> 1, wn = wv & 1;
    int bm = blockIdx.y * 128, bn = blockIdx.x * 128;

    // staging: wave wv covers rows wv*32 .. wv*32+32 of each 128x32 tile
    int rbase = wv * 32;
    int srow = lane >> 2;
    int scol = (lane & 3) * 8;
    const size_t aoff0 = (size_t)(bm + rbase + srow) * K + scol;
    const size_t aoff1 = aoff0 + (size_t)16 * K;
    const size_t boff0 = (size_t)(bn + rbase + srow) * K + scol;
    const size_t boff1 = boff0 + (size_t)16 * K;
    unsigned short* lA0 = &sAh[rbase * 32];
    unsigned short* lA1 = &sAh[(rbase + 16) * 32];
    unsigned short* lAl0 = &sAl[rbase * 32];
    unsigned short* lAl1 = &sAl[(rbase + 16) * 32];
    unsigned short* lB0 = &sBh[rbase * 32];
    unsigned short* lB1 = &sBh[(rbase + 16) * 32];
    unsigned short* lBl0 = &sBl[rbase * 32];
    unsigned short* lBl1 = &sBl[(rbase + 16) * 32];

    f32x4 acc[4][4];
    #pragma unroll
    for (int i = 0; i < 4; i++)
        #pragma unroll
        for (int j = 0; j < 4; j++)
            acc[i][j] = (f32x4){0.f, 0.f, 0.f, 0.f};

    int fr = lane & 15, q8 = (lane >> 4) * 8;

    for (int k0 = 0; k0 < K; k0 += 32) {
        gload16(Ahi + aoff0 + k0, lA0);
        gload16(Ahi + aoff1 + k0, lA1);
        gload16(Alo + aoff0 + k0, lAl0);
        gload16(Alo + aoff1 + k0, lAl1);
        gload16(Bhi + boff0 + k0, lB0);
        gload16(Bhi + boff1 + k0, lB1);
        gload16(Blo + boff0 + k0, lBl0);
        gload16(Blo + boff1 + k0, lBl1);
        __syncthreads();

        bf16x8 ah[4], al[4], bh[4], bl[4];
        #pragma unroll
        for (int t = 0; t < 4; t++) {
            ah[t] = *(const bf16x8*)&sAh[(wm * 64 + t * 16 + fr) * 32 + q8];
            al[t] = *(const bf16x8*)&sAl[(wm * 64 + t * 16 + fr) * 32 + q8];
            bh[t] = *(const bf16x8*)&sBh[(wn * 64 + t * 16 + fr) * 32 + q8];
            bl[t] = *(const bf16x8*)&sBl[(wn * 64 + t * 16 + fr) * 32 + q8];
        }
        #pragma unroll
        for (int i = 0; i < 4; i++)
            #pragma unroll
            for (int j = 0; j < 4; j++) {
                acc[i][j] = __builtin_amdgcn_mfma_f32_16x16x32_bf16(ah[i], bh[j], acc[i][j], 0, 0, 0);
                acc[i][j] = __builtin_amdgcn_mfma_f32_16x16x32_bf16(al[i], bh[j], acc[i][j], 0, 0, 0);
                acc[i][j] = __builtin_amdgcn_mfma_f32_16x16x32_bf16(ah[i], bl[j], acc[i][j], 0, 0, 0);
            }
        __syncthreads();
    }

    // epilogue: C/D layout col=lane&15, row=(lane>>4)*4+reg
    int q4 = (lane >> 4) * 4, c16 = lane & 15;
    #pragma unroll
    for (int i = 0; i < 4; i++)
        #pragma unroll
        for (int j = 0; j < 4; j++) {
            f32x4 v = acc[i][j];
            int col = bn + wn * 64 + j * 16 + c16;
            float bv = (flags & FLAG_BIAS) ? bias[col] : 0.f;
            #pragma unroll
            for (int r = 0; r < 4; r++) {
                int row = bm + wm * 64 + i * 16 + q4 + r;
                float val = v[r] + bv;
                if (flags & FLAG_KT) {
                    int bi = row >> 10, jj = row & 1023;
                    int hh = col >> 8, dk2 = col & 255;
                    C[((size_t)((bi * NH + hh) * DKH + dk2)) * SEQ + jj] = val;
                } else {
                    C[(size_t)row * N + col] = val;
                }
            }
        }
}

// ---------------- fp32 GEMM (small shapes) ----------------
#define BM 64
#define BN 64
#define BK 16
__global__ __launch_bounds__(256) void gemm_f32(
    const float* __restrict__ A, const float* __restrict__ B,
    const float* __restrict__ bias, float* __restrict__ C,
    int M, int N, int K, int lda, int ldb, int ldc, int flags)
{
    __shared__ float As[BK][BM + 4];
    __shared__ float Bs[BK][BN + 4];
    int tid = threadIdx.x;
    int tm = tid >> 4, tn = tid & 15;
    int bm = blockIdx.y * BM, bn = blockIdx.x * BN;
    float acc[4][4] = {};

    for (int k0 = 0; k0 < K; k0 += BK) {
        #pragma unroll
        for (int i = 0; i < 4; i++) {
            int idx = tid + i * 256;
            int r = idx >> 4, c = idx & 15;
            int gr = bm + r, gc = k0 + c;
            float v = 0.f;
            if (gr < M && gc < K) v = A[(size_t)gr * lda + gc];
            As[c][r] = v;
        }
        #pragma unroll
        for (int i = 0; i < 4; i++) {
            int idx = tid + i * 256;
            int r = idx >> 6, c = idx & 63;
            int gr = k0 + r, gc = bn + c;
            float v = 0.f;
            if (gr < K && gc < N) v = B[(size_t)gr * ldb + gc];
            Bs[r][c] = v;
        }
        __syncthreads();
        #pragma unroll
        for (int kk = 0; kk < BK; kk++) {
            float4 a4 = *(const float4*)&As[kk][tm * 4];
            float4 b4 = *(const float4*)&Bs[kk][tn * 4];
            float av[4] = {a4.x, a4.y, a4.z, a4.w};
            float bv[4] = {b4.x, b4.y, b4.z, b4.w};
            #pragma unroll
            for (int i = 0; i < 4; i++)
                #pragma unroll
                for (int j = 0; j < 4; j++)
                    acc[i][j] += av[i] * bv[j];
        }
        __syncthreads();
    }

    #pragma unroll
    for (int i = 0; i < 4; i++) {
        int row = bm + tm * 4 + i;
        if (row >= M) continue;
        #pragma unroll
        for (int j = 0; j < 4; j++) {
            int col = bn + tn * 4 + j;
            if (col >= N) continue;
            float val = acc[i][j];
            if (flags & FLAG_BIAS) val += bias[col];
            if (flags & FLAG_SOFTPLUS) val = (val > 20.f) ? val : log1pf(__expf(val));
            C[(size_t)row * ldc + col] = val;
        }
    }
}

// ---------------- attention (fp32, writes bf16 hi/lo) ----------------
#define TQ 8
__global__ __launch_bounds__(256) void attention(
    const float* __restrict__ q, const float* __restrict__ kt,
    const float* __restrict__ v, unsigned short* __restrict__ atthi,
    unsigned short* __restrict__ attlo)
{
    __shared__ float qs[TQ][DKH];
    __shared__ float sc[TQ][SEQ];
    __shared__ float rowstat[TQ];
    __shared__ float red[8];

    int tid = threadIdx.x;
    int bidx = blockIdx.x;
    int qt = bidx & 127;
    int h = (bidx >> 7) & 7;
    int b = bidx >> 10;
    int q0 = qt * TQ;

    #pragma unroll
    for (int r = 0; r < TQ; r++)
        qs[r][tid] = q[((size_t)(b * SEQ + q0 + r)) * DMODEL + h * DKH + tid];
    __syncthreads();

    {
        float acc[TQ][4] = {};
        const float* kbase = kt + ((size_t)(b * NH + h)) * DKH * SEQ + 4 * tid;
        for (int d = 0; d < DKH; d++) {
            float4 kv = *(const float4*)(kbase + (size_t)d * SEQ);
            #pragma unroll
            for (int r = 0; r < TQ; r++) {
                float qv = qs[r][d];
                acc[r][0] += qv * kv.x; acc[r][1] += qv * kv.y;
                acc[r][2] += qv * kv.z; acc[r][3] += qv * kv.w;
            }
        }
        #pragma unroll
        for (int r = 0; r < TQ; r++) {
            sc[r][4 * tid + 0] = acc[r][0] * 0.0625f;
            sc[r][4 * tid + 1] = acc[r][1] * 0.0625f;
            sc[r][4 * tid + 2] = acc[r][2] * 0.0625f;
            sc[r][4 * tid + 3] = acc[r][3] * 0.0625f;
        }
    }
    __syncthreads();

    for (int r = 0; r < TQ; r++) {
        float m = -1e30f;
        for (int j = tid; j < SEQ; j += 256) m = fmaxf(m, sc[r][j]);
        #pragma unroll
        for (int off = 1; off < 64; off <<= 1) m = fmaxf(m, __shfl_xor(m, off));
        if ((tid & 63) == 0) red[tid >> 6] = m;
        __syncthreads();
        m = fmaxf(fmaxf(red[0], red[1]), fmaxf(red[2], red[3]));
        __syncthreads();
        float s = 0.f;
        for (int j = tid; j < SEQ; j += 256) {
            float e = __expf(sc[r][j] - m);
            sc[r][j] = e;
            s += e;
        }
        #pragma unroll
        for (int off = 1; off < 64; off <<= 1) s += __shfl_xor(s, off);
        if ((tid & 63) == 0) red[tid >> 6] = s;
        __syncthreads();
        if (tid == 0) rowstat[r] = 1.f / (red[0] + red[1] + red[2] + red[3]);
        __syncthreads();
    }

    {
        float acc[TQ] = {};
        const float* vbase = v + (size_t)b * SEQ * DMODEL + h * DKH + tid;
        for (int j0 = 0; j0 < SEQ; j0 += 4) {
            float vv0 = vbase[(size_t)(j0 + 0) * DMODEL];
            float vv1 = vbase[(size_t)(j0 + 1) * DMODEL];
            float vv2 = vbase[(size_t)(j0 + 2) * DMODEL];
            float vv3 = vbase[(size_t)(j0 + 3) * DMODEL];
            #pragma unroll
            for (int r = 0; r < TQ; r++) {
                float4 p = *(const float4*)&sc[r][j0];
                acc[r] += p.x * vv0 + p.y * vv1 + p.z * vv2 + p.w * vv3;
            }
        }
        #pragma unroll
        for (int r = 0; r < TQ; r++) {
            float val = acc[r] * rowstat[r];
            size_t o = ((size_t)(b * SEQ + q0 + r)) * DMODEL + h * DKH + tid;
            unsigned short hh = f2bf(val);
            atthi[o] = hh;
            attlo[o] = f2bf(val - bf2f(hh));
        }
    }
}

// ---------------- mamba scan (unchanged) ----------------
__global__ __launch_bounds__(256) void mamba_scan(
    float* __restrict__ xz, const float* __restrict__ dt,
    const float* __restrict__ dbc, const float* __restrict__ A_log,
    const float* __restrict__ conv_w, const float* __restrict__ conv_b,
    const float* __restrict__ D_skip)
{
    int tid = threadIdx.x;
    int n = tid & 15;
    int dd = tid >> 4;
    int gb = blockIdx.x;
    int b = gb >> 8;
    int d = ((gb & 255) << 4) + dd;

    float A_n = -__expf(A_log[d * DSTATE + n]);
    float cw0 = conv_w[d * 4 + 0], cw1 = conv_w[d * 4 + 1];
    float cw2 = conv_w[d * 4 + 2], cw3 = conv_w[d * 4 + 3];
    float cb = conv_b[d];
    float dsk = D_skip[d];

    float h = 0.f;
    float w0 = 0.f, w1 = 0.f, w2 = 0.f;
    size_t rowx = (size_t)b * SEQ * 8192 + d;
    size_t rowdt = (size_t)b * SEQ * DINNER + d;
    size_t rowbc = (size_t)b * SEQ * 160;

    for (int t = 0; t < SEQ; t++) {
        float xr = xz[rowx + (size_t)t * 8192];
        float dtv = dt[rowdt + (size_t)t * DINNER];
        float Bv = dbc[rowbc + t * 160 + DTRANK + n];
        float Cv = dbc[rowbc + t * 160 + DTRANK + DSTATE + n];

        float xc = cw0 * w0 + cw1 * w1 + cw2 * w2 + cw3 * xr + cb;
        w0 = w1; w1 = w2; w2 = xr;
        float xs = xc / (1.f + __expf(-xc));

        float dA = __expf(dtv * A_n);
        h = dA * h + dtv * Bv * xs;
        float p = h * Cv;
        p += __shfl_xor(p, 1, 16);
        p += __shfl_xor(p, 2, 16);
        p += __shfl_xor(p, 4, 16);
        p += __shfl_xor(p, 8, 16);

        float y = p + dsk * xs;
        float zv = xz[rowx + (size_t)t * 8192 + DINNER];
        y = y * (zv / (1.f + __expf(-zv)));
        if (n == 0) xz[rowx + (size_t)t * 8192] = y;
    }
}

// ---------------- launcher ----------------
extern "C" void kernel_launch(void* const* d_in, const int* in_sizes, int n_in,
                              void* d_out, int out_size, void* d_ws, size_t ws_size,
                              hipStream_t stream) {
    const float* imgF   = (const float*)d_in[0];
    const float* kf     = (const float*)d_in[1];
    const float* Wq     = (const float*)d_in[2];
    const float* bq     = (const float*)d_in[3];
    const float* Wk     = (const float*)d_in[4];
    const float* bk     = (const float*)d_in[5];
    const float* Wv     = (const float*)d_in[6];
    const float* bv     = (const float*)d_in[7];
    const float* Wo     = (const float*)d_in[8];
    const float* bo     = (const float*)d_in[9];
    const float* W_in   = (const float*)d_in[10];
    const float* conv_w = (const float*)d_in[11];
    const float* conv_b = (const float*)d_in[12];
    const float* W_extra= (const float*)d_in[13];
    const float* W_xproj= (const float*)d_in[14];
    const float* W_dt   = (const float*)d_in[15];
    const float* b_dt   = (const float*)d_in[16];
    const float* A_log  = (const float*)d_in[17];
    const float* D_skip = (const float*)d_in[18];
    const float* W_out  = (const float*)d_in[19];
    float* out = (float*)d_out;
    char* W = (char*)d_ws;

    #define WS_F(off) ((float*)(W + (off)))
    #define WS_U(off) ((unsigned short*)(W + (off)))

    dim3 blk(256);
    auto gg = [](int M, int N) { return dim3((N + BN - 1) / BN, (M + BM - 1) / BM); };

    // ===== mamba phase =====
    // imgF -> bf16 hi/lo
    cvt_hilo<<<dim3(16384), blk, 0, stream>>>(imgF, WS_U(O_IMGH), WS_U(O_IMGL), 4194304);
    // W_in (2048x8192) -> W_in^T hi/lo
    tcvt<<<dim3(8192/32, 2048/32), blk, 0, stream>>>(W_in, WS_U(O_WINTH), WS_U(O_WINTL), 2048, 8192);
    // xz = imgF @ W_in   (M=8192, N=8192, K=2048)
    gemm_mfma3<<<dim3(64, 64), blk, 0, stream>>>(WS_U(O_IMGH), WS_U(O_IMGL),
        WS_U(O_WINTH), WS_U(O_WINTL), nullptr, WS_F(O_XZ), 8192, 8192, 2048, 0);
    // Wcomb = W_extra @ W_xproj   (2048x160, K=4096)
    gemm_f32<<<gg(2048, 160), blk, 0, stream>>>(W_extra, W_xproj, nullptr, WS_F(O_WCOMB),
        2048, 160, 4096, 4096, 160, 160, 0);
    // dbc = kf @ Wcomb
    gemm_f32<<<gg(8192, 160), blk, 0, stream>>>(kf, WS_F(O_WCOMB), nullptr, WS_F(O_DBC),
        8192, 160, 2048, 2048, 160, 160, 0);
    // dt = softplus(dbc[:, :128] @ W_dt + b_dt)
    gemm_f32<<<gg(8192, 4096), blk, 0, stream>>>(WS_F(O_DBC), W_dt, b_dt, WS_F(O_DT),
        8192, 4096, 128, 160, 4096, 4096, FLAG_BIAS | FLAG_SOFTPLUS);
    // fused conv + scan + gating (in place over x)
    mamba_scan<<<dim3(2048), blk, 0, stream>>>(WS_F(O_XZ), WS_F(O_DT), WS_F(O_DBC),
        A_log, conv_w, conv_b, D_skip);
    // y -> bf16 hi/lo (packed 8192x4096)
    ycvt<<<dim3(32768), blk, 0, stream>>>(WS_F(O_XZ), WS_U(O_YH), WS_U(O_YL));
    // W_out (4096x2048) -> W_out^T hi/lo
    tcvt<<<dim3(2048/32, 4096/32), blk, 0, stream>>>(W_out, WS_U(O_WOUTH), WS_U(O_WOUTL), 4096, 2048);
    // out1 = y @ W_out   (M=8192, N=2048, K=4096)
    gemm_mfma3<<<dim3(16, 64), blk, 0, stream>>>(WS_U(O_YH), WS_U(O_YL),
        WS_U(O_WOUTH), WS_U(O_WOUTL), nullptr, out + 16777216, 8192, 2048, 4096, 0);

    // ===== attention phase =====
    cvt_hilo<<<dim3(16384), blk, 0, stream>>>(imgF, WS_U(O_IMGH2), WS_U(O_IMGL2), 4194304);
    tcvt<<<dim3(64, 64), blk, 0, stream>>>(Wq, WS_U(O_WQH), WS_U(O_WQL), 2048, 2048);
    tcvt<<<dim3(64, 64), blk, 0, stream>>>(Wk, WS_U(O_WKH), WS_U(O_WKL), 2048, 2048);
    tcvt<<<dim3(64, 64), blk, 0, stream>>>(Wv, WS_U(O_WVH), WS_U(O_WVL), 2048, 2048);
    tcvt<<<dim3(64, 64), blk, 0, stream>>>(Wo, WS_U(O_WOH), WS_U(O_WOL), 2048, 2048);
    // q = imgF @ Wq + bq
    gemm_mfma3<<<dim3(16, 64), blk, 0, stream>>>(WS_U(O_IMGH2), WS_U(O_IMGL2),
        WS_U(O_WQH), WS_U(O_WQL), bq, WS_F(O_QF), 8192, 2048, 2048, FLAG_BIAS);
    // kT = (imgF @ Wk + bk) transposed per (b,h)
    gemm_mfma3<<<dim3(16, 64), blk, 0, stream>>>(WS_U(O_IMGH2), WS_U(O_IMGL2),
        WS_U(O_WKH), WS_U(O_WKL), bk, WS_F(O_KTF), 8192, 2048, 2048, FLAG_BIAS | FLAG_KT);
    // v = imgF @ Wv + bv
    gemm_mfma3<<<dim3(16, 64), blk, 0, stream>>>(WS_U(O_IMGH2), WS_U(O_IMGL2),
        WS_U(O_WVH), WS_U(O_WVL), bv, WS_F(O_VF), 8192, 2048, 2048, FLAG_BIAS);
    // attention -> att bf16 hi/lo
    attention<<<dim3(BSZ * NH * (SEQ / TQ)), blk, 0, stream>>>(
        WS_F(O_QF), WS_F(O_KTF), WS_F(O_VF), WS_U(O_ATTH), WS_U(O_ATTL));
    // out0 = att @ Wo + bo
    gemm_mfma3<<<dim3(16, 64), blk, 0, stream>>>(WS_U(O_ATTH), WS_U(O_ATTL),
        WS_U(O_WOH), WS_U(O_WOL), bo, out, 8192, 2048, 2048, FLAG_BIAS);
}